// Round 4
// baseline (101.313 us; speedup 1.0000x reference)
//
#include <hip/hip_runtime.h>
#include <math.h>

// monotonic_binary_output: out[r] = (u[r] < sigmoid-thresh[r]).
//
// v4: barrier-free global_load_lds pipeline.
//  - 1 wave/block; each wave double-buffers a private 16-row chunk in LDS.
//  - chunk = 16 rows x 129 floats = 8256 B, always 16B-aligned (8256%16==0),
//    so the DMA sources are aligned dwordx4 even though rows are 516 B.
//  - counted s_waitcnt vmcnt(10): the 10 prefetch DMAs for chunk t+1 stay in
//    flight while chunk t is computed (never drain to 0 in the loop).
//  - u is DMA-staged too, so the loop's only compiler VMEM is the out store:
//    manual vmcnt accounting stays exact (10 prefetch + 1 older store).
//  - numerics: f32 hot path + rare f64 escape (re-reads x from global),
//    identical decisions to the pure-f64 kernel (absmax == 0.0 in R1-R3).

constexpr int LATENT = 128;
constexpr int RS     = 129;          // x row stride in floats
constexpr int CH     = 16;           // rows per chunk
constexpr int CHF    = CH * RS;      // 2064 floats = 8256 B per chunk
constexpr int CPL    = 8;            // cols per lane (16 lanes per row)
constexpr int ROWS   = 4;            // rows per 16-lane group

typedef float __attribute__((address_space(1))) gfloat;
typedef float __attribute__((address_space(3))) sfloat;

__device__ __forceinline__ void stage_chunk(const float* xg, const float* ug,
                                            float* lx, float* lu, int lane) {
    // 8 full wave-wide 1KB DMAs: floats [256k + 4*lane, +4)
#pragma unroll
    for (int k = 0; k < 8; ++k) {
        __builtin_amdgcn_global_load_lds((const gfloat*)(xg + 256 * k + 4 * lane),
                                         (sfloat*)(lx + 256 * k), 16, 0, 0);
    }
    // tail: floats 2048..2063 (4 lanes) + the 16-float u chunk (4 lanes)
    if (lane < 4) {
        __builtin_amdgcn_global_load_lds((const gfloat*)(xg + 2048 + 4 * lane),
                                         (sfloat*)(lx + 2048), 16, 0, 0);
        __builtin_amdgcn_global_load_lds((const gfloat*)(ug + 4 * lane),
                                         (sfloat*)lu, 16, 0, 0);
    }
}

__global__ __launch_bounds__(64, 1)
void mono_kernel(const float* __restrict__ x,
                 const float* __restrict__ W,
                 const float* __restrict__ b,
                 const float* __restrict__ u,
                 float* __restrict__ out,
                 int N)
{
    __shared__ __align__(16) float lx[2][CHF];
    __shared__ __align__(16) float lu[2][CH];

    const int lane = threadIdx.x;        // 0..63 (one wave per block)
    const int sub  = lane & 15;          // lane within 16-lane row-group
    const int gi   = lane >> 4;          // group 0..3 -> rows 4gi..4gi+3
    const int w    = blockIdx.x;         // wave id
    const int nw   = gridDim.x;
    const int NC   = N / CH;             // 62500 chunks

    // Lane's weight slice: cols c = sub + 16j (f32, exact copies of W).
    float w0f[CPL], w1f[CPL];
#pragma unroll
    for (int j = 0; j < CPL; ++j) {
        const int c = sub + 16 * j;
        w0f[j] = W[2 * c + 0];
        w1f[j] = W[2 * c + 1];
    }
    const float b0f = b[0], b1f = b[1];

    int cur = 0;
    if (w < NC)
        stage_chunk(x + (size_t)w * CHF, u + (size_t)w * CH, lx[0], lu[0], lane);

    for (int c = w; c < NC; c += nw) {
        const int cn = c + nw;
        if (cn < NC) {
            stage_chunk(x + (size_t)cn * CHF, u + (size_t)cn * CH,
                        lx[cur ^ 1], lu[cur ^ 1], lane);
            // 10 newest (next-chunk DMAs) may stay outstanding; everything
            // older -- including this buffer's 10 DMAs -- must have landed.
            asm volatile("s_waitcnt vmcnt(10)" ::: "memory");
        } else {
            asm volatile("s_waitcnt vmcnt(0)" ::: "memory");
        }

        const float* L  = lx[cur];
        const float* Lu = lu[cur];

        // ---- LDS -> regs (16 consecutive floats per group-instr: <=2-way) ----
        float fa[ROWS][CPL], zz[ROWS], uu[ROWS];
#pragma unroll
        for (int i = 0; i < ROWS; ++i) {
            const float* Lr = L + (4 * gi + i) * RS;
#pragma unroll
            for (int j = 0; j < CPL; ++j) fa[i][j] = Lr[sub + 16 * j];
            zz[i] = Lr[LATENT];
            uu[i] = Lu[4 * gi + i];
        }

        // ---- f32 dot: 8 independent FMA chains ----
        float s0[ROWS], s1[ROWS];
#pragma unroll
        for (int i = 0; i < ROWS; ++i) { s0[i] = 0.0f; s1[i] = 0.0f; }
#pragma unroll
        for (int j = 0; j < CPL; ++j) {
#pragma unroll
            for (int i = 0; i < ROWS; ++i) {
                s0[i] = fmaf(fa[i][j], w0f[j], s0[i]);
                s1[i] = fmaf(fa[i][j], w1f[j], s1[i]);
            }
        }

        // ---- butterfly reduce within 16-lane group ----
#pragma unroll
        for (int m = 8; m >= 1; m >>= 1) {
#pragma unroll
            for (int i = 0; i < ROWS; ++i) {
                s0[i] += __shfl_xor(s0[i], m, 64);
                s1[i] += __shfl_xor(s1[i], m, 64);
            }
        }

        // ---- f32 decision + conservative escalation ----
        float oo[ROWS];
        bool esc = false;
#pragma unroll
        for (int i = 0; i < ROWS; ++i) {
            const float l0 = s0[i] + b0f;
            const float l1 = s1[i] + b1f;
            const float t  = (zz[i] == 1.0f) ? fmaxf(l0, l1) : fminf(l0, l1);
            const float q  = uu[i] * (1.0f + expf(-t));
            oo[i] = (q < 1.0f) ? 1.0f : 0.0f;
            esc = esc || (fabsf(q - 1.0f) < 2.5e-4f * (1.0f + q));
        }

        // ---- rare exact f64 recompute (reloads x from global) ----
        if (__builtin_expect(esc, 0)) {
#pragma unroll 1
            for (int i = 0; i < ROWS; ++i) {
                const float* xr = x + (size_t)(c * CH + 4 * gi + i) * RS;
                double d0 = 0.0, d1 = 0.0;
#pragma unroll
                for (int j = 0; j < CPL; ++j) {
                    const double xv = (double)xr[sub + 16 * j];
                    d0 = fma(xv, (double)w0f[j], d0);
                    d1 = fma(xv, (double)w1f[j], d1);
                }
#pragma unroll
                for (int m = 8; m >= 1; m >>= 1) {
                    d0 += __shfl_xor(d0, m, 64);
                    d1 += __shfl_xor(d1, m, 64);
                }
                const double l0 = d0 + (double)b0f;
                const double l1 = d1 + (double)b1f;
                const double t  = (zz[i] == 1.0f) ? fmax(l0, l1) : fmin(l0, l1);
                oo[i] = ((double)uu[i] * (1.0 + exp(-t)) < 1.0) ? 1.0f : 0.0f;
            }
        }

        if (sub == 0) {
            *reinterpret_cast<float4*>(out + c * CH + 4 * gi) =
                make_float4(oo[0], oo[1], oo[2], oo[3]);
        }
        cur ^= 1;
    }
}

extern "C" void kernel_launch(void* const* d_in, const int* in_sizes, int n_in,
                              void* d_out, int out_size, void* d_ws, size_t ws_size,
                              hipStream_t stream) {
    const float* x = (const float*)d_in[0];
    const float* W = (const float*)d_in[1];
    const float* b = (const float*)d_in[2];
    const float* u = (const float*)d_in[3];
    float* out = (float*)d_out;
    const int N = in_sizes[3];   // u has N elements

    // 1 wave/block; LDS 16.6 KB/block -> 8 blocks/CU at grid 2048 (256 CUs).
    mono_kernel<<<2048, 64, 0, stream>>>(x, W, b, u, out, N);
}